// Round 9
// baseline (1305.312 us; speedup 1.0000x reference)
//
#include <hip/hip_runtime.h>
#include <hip/hip_bf16.h>

#define B_ 4
#define S_ 2048
#define DIN 2048
#define DST 2048
#define DOUT 2048
#define NH 16
#define HH 128
#define M_ (B_ * S_)          // 8192
#define OUT_OFF ((size_t)M_ * DOUT)  // 16777216

// ws layout — all sizes verified:
//   hs  [8192][2048] bf16 = 33,554,432 B
//   wit [2048][2048] bf16 =  8,388,608 B
//   wot [2048][2048] bf16 =  8,388,608 B
//   xp  [8192][2048] f16  = 33,554,432 B
//   flags: 4 KB + 256 B
#define WS_HS    0u
#define WS_WIT   33554432u
#define WS_WOT   41943040u
#define WS_XP    50331648u
#define WS_FLAGS 83886080u    // end 83,894,272 << proven >=112 MB

typedef __attribute__((ext_vector_type(8))) __bf16 bf16x8;
typedef __attribute__((ext_vector_type(4))) float f32x4;
typedef __attribute__((ext_vector_type(2))) _Float16 f16x2;

__device__ __forceinline__ unsigned short f2bf(float f) {
    unsigned int u = __float_as_uint(f);
    unsigned int r = u + 0x7FFFu + ((u >> 16) & 1u);
    return (unsigned short)(r >> 16);
}

__device__ __forceinline__ float fdot2(f16x2 a, f16x2 b, float c) {
#if __has_builtin(__builtin_amdgcn_fdot2)
    return __builtin_amdgcn_fdot2(a, b, c, false);
#else
    return fmaf((float)a.x, (float)b.x, fmaf((float)a.y, (float)b.y, c));
#endif
}

#define DPP_PULL(v, ctrl) __builtin_bit_cast(float, \
    __builtin_amdgcn_mov_dpp(__builtin_bit_cast(int, (v)), (ctrl), 0xf, 0xf, true))

__device__ __forceinline__ void gload_lds16(const void* g, void* l) {
    __builtin_amdgcn_global_load_lds(
        (const __attribute__((address_space(1))) void*)g,
        (__attribute__((address_space(3))) void*)l, 16, 0, 0);
}

__device__ __forceinline__ void wait_flag(const unsigned* p, unsigned v) {
    if (threadIdx.x == 0) {
        while (__hip_atomic_load(p, __ATOMIC_ACQUIRE, __HIP_MEMORY_SCOPE_AGENT) < v)
            __builtin_amdgcn_s_sleep(8);
    }
    __syncthreads();
}

// ------------- transpose + cast: in[K][N] fp32 -> out[N][K] bf16 -------------
__global__ __launch_bounds__(256) void k_transpose_bf16(
    const float* __restrict__ in, unsigned short* __restrict__ out, int K, int N) {
    __shared__ float tile[64][65];
    int k0 = blockIdx.y * 64, n0 = blockIdx.x * 64;
    int tr  = threadIdx.x >> 4;
    int tc4 = (threadIdx.x & 15) * 4;
#pragma unroll
    for (int p = 0; p < 4; ++p) {
        int r = tr + p * 16;
        float4 v = *(const float4*)&in[(size_t)(k0 + r) * N + n0 + tc4];
        tile[r][tc4 + 0] = v.x; tile[r][tc4 + 1] = v.y;
        tile[r][tc4 + 2] = v.z; tile[r][tc4 + 3] = v.w;
    }
    __syncthreads();
#pragma unroll
    for (int p = 0; p < 4; ++p) {
        int n = tr + p * 16;
        ushort4 o;
        o.x = f2bf(tile[tc4 + 0][n]); o.y = f2bf(tile[tc4 + 1][n]);
        o.z = f2bf(tile[tc4 + 2][n]); o.w = f2bf(tile[tc4 + 3][n]);
        *(ushort4*)&out[(size_t)(n0 + n) * K + k0 + tc4] = o;
    }
}

// =============== MEGA KERNEL: scan(0..63) | gemm1(64..159) | gemm2(160..255) ===============
__global__ __attribute__((amdgpu_flat_work_group_size(256, 256),
                          amdgpu_waves_per_eu(1, 1))) void k_mega(
    const float* __restrict__ x,         // [M_][DIN] fp32
    const float* __restrict__ h0,        // [B_][DST]
    const float* __restrict__ sw,        // [NH][HH][HH]
    const float* __restrict__ bias,      // [DST]
    const unsigned short* __restrict__ wit,
    const unsigned short* __restrict__ wot,
    unsigned short* __restrict__ xpf,    // f16 [M_][DST]
    unsigned short* __restrict__ hs,     // bf16 [M_][DST]
    float* __restrict__ out,
    float* __restrict__ out_state,
    unsigned* __restrict__ flags1,       // [1024] per xp tile (c*64+b*16+n)
    unsigned* __restrict__ flags2) {     // [64]   per (b,c) hs chunk, counts to 16
    __shared__ unsigned short As[128 * 64];
    __shared__ unsigned short Bs[128 * 64];
    __shared__ __align__(16) unsigned hb[2][64];
    const int blk = blockIdx.x;
    const int tid = threadIdx.x;
    const int lane = tid & 63;
    const int wid  = tid >> 6;

    if (blk < 64) {
        // ---------------- SCAN (r5 core, chunked with flags) ----------------
        const int G  = wid * 16 + (lane >> 2);
        const int q  = lane & 3;
        const int c0 = G * 2;
        const int bb = blk >> 4;
        const int nn = blk & 15;

        const float* wbp = sw + (size_t)nn * HH * HH + (size_t)(q * 32) * HH + c0;
#define MKW(j) f16x2 wA##j, wB##j; { const float* pw = wbp + (size_t)(2 * (j)) * HH; \
        wA##j = f16x2{(_Float16)pw[0], (_Float16)pw[HH]};                            \
        wB##j = f16x2{(_Float16)pw[1], (_Float16)pw[HH + 1]}; }
        MKW(0)  MKW(1)  MKW(2)  MKW(3)  MKW(4)  MKW(5)  MKW(6)  MKW(7)
        MKW(8)  MKW(9)  MKW(10) MKW(11) MKW(12) MKW(13) MKW(14) MKW(15)
#undef MKW

        if (tid < 64) {
            float2 h2 = *(const float2*)(h0 + bb * DST + nn * HH + 2 * tid);
            unsigned lo = __builtin_bit_cast(unsigned short, (_Float16)h2.x);
            unsigned hi = __builtin_bit_cast(unsigned short, (_Float16)h2.y);
            hb[0][tid] = lo | (hi << 16);
        }

        const unsigned* xH = (const unsigned*)(xpf + (size_t)bb * S_ * DST + nn * HH) + G;
        unsigned* hrow32 = (unsigned*)(hs + (size_t)bb * S_ * DST + nn * HH) + G;
        float* osp = out_state + bb * DST + nn * HH + c0;

        wait_flag(&flags1[0 * 64 + bb * 16 + nn], 1);
        wait_flag(&flags1[1 * 64 + bb * 16 + nn], 1);

        unsigned xh0 = xH[0], xh1 = xH[1024], xh2 = xH[2048], xh3 = xH[3072];

        asm volatile("s_waitcnt lgkmcnt(0)\ns_barrier" ::: "memory");

        int p = 0;
        for (int c = 0; c < 16; ++c) {
            if (c >= 1) {
                int cn = (c + 1 > 15) ? 15 : c + 1;
                wait_flag(&flags1[cn * 64 + bb * 16 + nn], 1);
            }
            for (int tt = 0; tt < 128; ++tt) {
                int t = c * 128 + tt;
                int tpf = (t + 4 < S_) ? t + 4 : S_ - 1;
                unsigned xh4 = xH[(size_t)tpf * 1024];

                const uint4* hp = (const uint4*)&hb[p][q * 16];
                uint4 Ra = hp[0], Rb = hp[1], Rc = hp[2], Rd = hp[3];

                float a0e = 0.f, a0o = 0.f, a1e = 0.f, a1o = 0.f;
#define D2(u, j, s) { f16x2 hj = __builtin_bit_cast(f16x2, (unsigned)(u)); \
        a0##s = fdot2(hj, wA##j, a0##s); a1##s = fdot2(hj, wB##j, a1##s); }
                D2(Ra.x, 0,  e) D2(Ra.y, 1,  o) D2(Ra.z, 2,  e) D2(Ra.w, 3,  o)
                D2(Rb.x, 4,  e) D2(Rb.y, 5,  o) D2(Rb.z, 6,  e) D2(Rb.w, 7,  o)
                D2(Rc.x, 8,  e) D2(Rc.y, 9,  o) D2(Rc.z, 10, e) D2(Rc.w, 11, o)
                D2(Rd.x, 12, e) D2(Rd.y, 13, o) D2(Rd.z, 14, e) D2(Rd.w, 15, o)
#undef D2
                float r0 = a0e + a0o;
                float r1 = a1e + a1o;
                r0 += DPP_PULL(r0, 0xB1); r0 += DPP_PULL(r0, 0x4E);
                r1 += DPP_PULL(r1, 0xB1); r1 += DPP_PULL(r1, 0x4E);

                f16x2 xv = __builtin_bit_cast(f16x2, xh0);
                float s0 = r0 + (float)xv.x;
                float s1 = r1 + (float)xv.y;
                float ssel = (lane & 1) ? s1 : s0;
                float e = __builtin_amdgcn_exp2f(ssel * 2.885390081777927f);
                float th = fmaf(-2.f, __builtin_amdgcn_rcpf(e + 1.f), 1.f);
                float uo = DPP_PULL(th, 0xB1);

                if (q == 0) {
                    unsigned lo16 = __builtin_bit_cast(unsigned short, (_Float16)th);
                    unsigned hi16 = __builtin_bit_cast(unsigned short, (_Float16)uo);
                    hb[p ^ 1][G] = lo16 | (hi16 << 16);
                    hrow32[(size_t)t * (DST / 2)] =
                        (unsigned)f2bf(th) | ((unsigned)f2bf(uo) << 16);
                    if (t == S_ - 1) { osp[0] = th; osp[1] = uo; }
                }
                asm volatile("s_waitcnt lgkmcnt(0)\ns_barrier" ::: "memory");
                p ^= 1;
                xh0 = xh1; xh1 = xh2; xh2 = xh3; xh3 = xh4;
            }
            asm volatile("s_waitcnt vmcnt(0)" ::: "memory");
            __syncthreads();
            if (tid == 0)
                __hip_atomic_fetch_add(&flags2[bb * 16 + c], 1u,
                                       __ATOMIC_RELEASE, __HIP_MEMORY_SCOPE_AGENT);
        }
        return;
    }

    // shared gemm lane decomposition
    const int wr = (wid >> 1), wc = (wid & 1);
    int srow[4], skb[4];
#pragma unroll
    for (int i = 0; i < 4; ++i) {
        unsigned o = (unsigned)(i * 256 + tid) * 16u;
        unsigned l = o ^ (((o >> 7) & 7u) << 4);
        srow[i] = (int)(l >> 7);
        skb[i]  = (int)(l & 127u);
    }

    if (blk < 160) {
        // -------- GEMM1 workers: xp(f16) = x @ wit^T + b, reg-staged A cast --------
        const int w = blk - 64;
        for (int T = w; T < 1024; T += 96) {
            int c = T >> 6, b = (T >> 4) & 3, n = T & 15;
            int row0 = b * 2048 + c * 128, col0 = n * 128;
            const float* Ab = x + (size_t)row0 * DIN;
            const char* Bb = (const char*)(wit + (size_t)col0 * DIN);

            f32x4 acc[4][4];
#pragma unroll
            for (int m = 0; m < 4; ++m)
#pragma unroll
                for (int nn2 = 0; nn2 < 4; ++nn2) acc[m][nn2] = (f32x4)(0.f);

            for (int kt = 0; kt < DIN; kt += 64) {
#pragma unroll
                for (int i = 0; i < 8; ++i) {
                    int idx = i * 256 + tid;          // float4 slot 0..2047
                    int row = idx >> 4;
                    int cc  = (idx & 15) * 4;
                    float4 v = *(const float4*)&Ab[(size_t)row * DIN + kt + cc];
                    ushort4 u;
                    u.x = f2bf(v.x); u.y = f2bf(v.y); u.z = f2bf(v.z); u.w = f2bf(v.w);
                    unsigned byte = (unsigned)(row * 128 + cc * 2);
                    byte ^= ((unsigned)(row & 7)) << 4;
                    *(ushort4*)((char*)As + byte) = u;
                }
#pragma unroll
                for (int i = 0; i < 4; ++i) {
                    unsigned o = (unsigned)(i * 256 + tid) * 16u;
                    gload_lds16(Bb + (size_t)srow[i] * (DIN * 2) + (size_t)kt * 2 + skb[i],
                                (char*)Bs + o);
                }
                asm volatile("s_waitcnt vmcnt(0)" ::: "memory");
                __syncthreads();
#pragma unroll
                for (int ks = 0; ks < 2; ++ks) {
                    bf16x8 af[4], bfr[4];
#pragma unroll
                    for (int m = 0; m < 4; ++m) {
                        int row = wr * 64 + m * 16 + (lane & 15);
                        unsigned o = (unsigned)(row * 128 + ks * 64 + ((lane >> 4) * 16));
                        o ^= ((unsigned)(row & 7) << 4);
                        af[m] = *(const bf16x8*)((const char*)As + o);
                    }
#pragma unroll
                    for (int nn2 = 0; nn2 < 4; ++nn2) {
                        int col = wc * 64 + nn2 * 16 + (lane & 15);
                        unsigned o = (unsigned)(col * 128 + ks * 64 + ((lane >> 4) * 16));
                        o ^= ((unsigned)(col & 7) << 4);
                        bfr[nn2] = *(const bf16x8*)((const char*)Bs + o);
                    }
#pragma unroll
                    for (int m = 0; m < 4; ++m)
#pragma unroll
                        for (int nn2 = 0; nn2 < 4; ++nn2)
                            acc[m][nn2] = __builtin_amdgcn_mfma_f32_16x16x32_bf16(
                                af[m], bfr[nn2], acc[m][nn2], 0, 0, 0);
                }
                __syncthreads();
            }
            // epilogue: +bias, f16 store
#pragma unroll
            for (int nn2 = 0; nn2 < 4; ++nn2) {
                int gcol = col0 + wc * 64 + nn2 * 16 + (lane & 15);
                float bv = bias[gcol];
#pragma unroll
                for (int m = 0; m < 4; ++m) {
                    int growb = row0 + wr * 64 + m * 16 + ((lane >> 4) * 4);
#pragma unroll
                    for (int r = 0; r < 4; ++r) {
                        float v = acc[m][nn2][r] + bv;
                        xpf[(size_t)(growb + r) * DST + gcol] =
                            __builtin_bit_cast(unsigned short, (_Float16)v);
                    }
                }
            }
            asm volatile("s_waitcnt vmcnt(0)" ::: "memory");
            __syncthreads();
            if (tid == 0)
                __hip_atomic_store(&flags1[T], 1u,
                                   __ATOMIC_RELEASE, __HIP_MEMORY_SCOPE_AGENT);
        }
    } else {
        // ---------------- GEMM2 workers: out = hs @ wot^T ----------------
        const int w = blk - 160;
        for (int T = w; T < 1024; T += 96) {
            int c = T >> 6, b = (T >> 4) & 3, ct = T & 15;
            wait_flag(&flags2[b * 16 + c], 16);
            int row0 = b * 2048 + c * 128, col0 = ct * 128;
            const char* Abase = (const char*)(hs + (size_t)row0 * DST);
            const char* Bbase = (const char*)(wot + (size_t)col0 * DST);

            f32x4 acc[4][4];
#pragma unroll
            for (int m = 0; m < 4; ++m)
#pragma unroll
                for (int nn2 = 0; nn2 < 4; ++nn2) acc[m][nn2] = (f32x4)(0.f);

            for (int kt = 0; kt < DST; kt += 64) {
#pragma unroll
                for (int i = 0; i < 4; ++i) {
                    unsigned o = (unsigned)(i * 256 + tid) * 16u;
                    gload_lds16(Abase + (size_t)srow[i] * (DST * 2) + (size_t)kt * 2 + skb[i],
                                (char*)As + o);
                    gload_lds16(Bbase + (size_t)srow[i] * (DST * 2) + (size_t)kt * 2 + skb[i],
                                (char*)Bs + o);
                }
                asm volatile("s_waitcnt vmcnt(0)" ::: "memory");
                __syncthreads();
#pragma unroll
                for (int ks = 0; ks < 2; ++ks) {
                    bf16x8 af[4], bfr[4];
#pragma unroll
                    for (int m = 0; m < 4; ++m) {
                        int row = wr * 64 + m * 16 + (lane & 15);
                        unsigned o = (unsigned)(row * 128 + ks * 64 + ((lane >> 4) * 16));
                        o ^= ((unsigned)(row & 7) << 4);
                        af[m] = *(const bf16x8*)((const char*)As + o);
                    }
#pragma unroll
                    for (int nn2 = 0; nn2 < 4; ++nn2) {
                        int col = wc * 64 + nn2 * 16 + (lane & 15);
                        unsigned o = (unsigned)(col * 128 + ks * 64 + ((lane >> 4) * 16));
                        o ^= ((unsigned)(col & 7) << 4);
                        bfr[nn2] = *(const bf16x8*)((const char*)Bs + o);
                    }
#pragma unroll
                    for (int m = 0; m < 4; ++m)
#pragma unroll
                        for (int nn2 = 0; nn2 < 4; ++nn2)
                            acc[m][nn2] = __builtin_amdgcn_mfma_f32_16x16x32_bf16(
                                af[m], bfr[nn2], acc[m][nn2], 0, 0, 0);
                }
                __syncthreads();
            }
#pragma unroll
            for (int nn2 = 0; nn2 < 4; ++nn2) {
                int gcol = col0 + wc * 64 + nn2 * 16 + (lane & 15);
#pragma unroll
                for (int m = 0; m < 4; ++m) {
                    int growb = row0 + wr * 64 + m * 16 + ((lane >> 4) * 4);
                    float* cp = out + (size_t)growb * DOUT + gcol;
#pragma unroll
                    for (int r = 0; r < 4; ++r) cp[(size_t)r * DOUT] = acc[m][nn2][r];
                }
            }
        }
    }
}

extern "C" void kernel_launch(void* const* d_in, const int* in_sizes, int n_in,
                              void* d_out, int out_size, void* d_ws, size_t ws_size,
                              hipStream_t stream) {
    const float* x    = (const float*)d_in[0];
    const float* h0   = (const float*)d_in[1];
    const float* Wi   = (const float*)d_in[2];
    const float* bias = (const float*)d_in[3];
    const float* sw   = (const float*)d_in[4];
    const float* Wo   = (const float*)d_in[5];
    float* out = (float*)d_out;

    char* ws = (char*)d_ws;
    unsigned short* hsb = (unsigned short*)(ws + WS_HS);
    unsigned short* wit = (unsigned short*)(ws + WS_WIT);
    unsigned short* wot = (unsigned short*)(ws + WS_WOT);
    unsigned short* xpf = (unsigned short*)(ws + WS_XP);
    unsigned* flags1 = (unsigned*)(ws + WS_FLAGS);
    unsigned* flags2 = flags1 + 1024;

    dim3 tg(32, 32);
    k_transpose_bf16<<<tg, 256, 0, stream>>>(Wi, wit, DIN, DST);
    k_transpose_bf16<<<tg, 256, 0, stream>>>(Wo, wot, DST, DOUT);
    hipMemsetAsync(ws + WS_FLAGS, 0, 8192, stream);
    k_mega<<<256, 256, 0, stream>>>(x, h0, sw, bias, wit, wot,
                                    xpf, hsb, out, out + OUT_OFF,
                                    flags1, flags2);
}

// Round 10
// 1019.312 us; speedup vs baseline: 1.2806x; 1.2806x over previous
//
#include <hip/hip_runtime.h>
#include <hip/hip_bf16.h>

#define B_ 4
#define S_ 2048
#define DIN 2048
#define DST 2048
#define DOUT 2048
#define NH 16
#define HH 128
#define M_ (B_ * S_)          // 8192
#define OUT_OFF ((size_t)M_ * DOUT)  // 16777216

typedef __attribute__((ext_vector_type(8))) __bf16 bf16x8;
typedef __attribute__((ext_vector_type(4))) float f32x4;
typedef __attribute__((ext_vector_type(2))) _Float16 f16x2;

__device__ __forceinline__ unsigned short f2bf(float f) {
    unsigned int u = __float_as_uint(f);
    unsigned int r = u + 0x7FFFu + ((u >> 16) & 1u);
    return (unsigned short)(r >> 16);
}
__device__ __forceinline__ unsigned pk16(_Float16 a, _Float16 b) {
    return (unsigned)__builtin_bit_cast(unsigned short, a) |
           ((unsigned)__builtin_bit_cast(unsigned short, b) << 16);
}

__device__ __forceinline__ float fdot2(f16x2 a, f16x2 b, float c) {
#if __has_builtin(__builtin_amdgcn_fdot2)
    return __builtin_amdgcn_fdot2(a, b, c, false);
#else
    return fmaf((float)a.x, (float)b.x, fmaf((float)a.y, (float)b.y, c));
#endif
}
__device__ __forceinline__ float fdu(unsigned h, unsigned w, float c) {
    return fdot2(__builtin_bit_cast(f16x2, h), __builtin_bit_cast(f16x2, w), c);
}

__device__ __forceinline__ void gload_lds16(const void* g, void* l) {
    __builtin_amdgcn_global_load_lds(
        (const __attribute__((address_space(1))) void*)g,
        (__attribute__((address_space(3))) void*)l, 16, 0, 0);
}

// ---------------- cast x (fp32 -> bf16), 8 elems/thread ----------------
__global__ __launch_bounds__(256) void k_cast_bf16(
    const float* __restrict__ in, unsigned short* __restrict__ out, int n8) {
    int i = blockIdx.x * 256 + threadIdx.x;
    if (i >= n8) return;
    const float4* p = ((const float4*)in) + (size_t)i * 2;
    float4 a = p[0], b = p[1];
    ushort4 r0, r1;
    r0.x = f2bf(a.x); r0.y = f2bf(a.y); r0.z = f2bf(a.z); r0.w = f2bf(a.w);
    r1.x = f2bf(b.x); r1.y = f2bf(b.y); r1.z = f2bf(b.z); r1.w = f2bf(b.w);
    ushort4* o = ((ushort4*)out) + (size_t)i * 2;
    o[0] = r0; o[1] = r1;
}

// ------------- transpose + cast: in[K][N] fp32 -> out[N][K] bf16 -------------
__global__ __launch_bounds__(256) void k_transpose_bf16(
    const float* __restrict__ in, unsigned short* __restrict__ out, int K, int N) {
    __shared__ float tile[64][65];
    int k0 = blockIdx.y * 64, n0 = blockIdx.x * 64;
    int tr  = threadIdx.x >> 4;
    int tc4 = (threadIdx.x & 15) * 4;
#pragma unroll
    for (int p = 0; p < 4; ++p) {
        int r = tr + p * 16;
        float4 v = *(const float4*)&in[(size_t)(k0 + r) * N + n0 + tc4];
        tile[r][tc4 + 0] = v.x; tile[r][tc4 + 1] = v.y;
        tile[r][tc4 + 2] = v.z; tile[r][tc4 + 3] = v.w;
    }
    __syncthreads();
#pragma unroll
    for (int p = 0; p < 4; ++p) {
        int n = tr + p * 16;
        ushort4 o;
        o.x = f2bf(tile[tc4 + 0][n]); o.y = f2bf(tile[tc4 + 1][n]);
        o.z = f2bf(tile[tc4 + 2][n]); o.w = f2bf(tile[tc4 + 3][n]);
        *(ushort4*)&out[(size_t)(n0 + n) * K + k0 + tc4] = o;
    }
}

// ------- bf16 GEMM: C = A[M][K] * Bt[N][K]^T ; outF16: +bias, f16 store -------
__global__ __launch_bounds__(256, 2) void k_gemm_bt(
    const unsigned short* __restrict__ A,
    const unsigned short* __restrict__ Bt,
    void* __restrict__ C,
    const float* __restrict__ bias,
    int M, int N, int K, int outF16) {
    __shared__ unsigned short As[128 * 64];
    __shared__ unsigned short Bs[128 * 64];
    const int tid  = threadIdx.x;
    const int lane = tid & 63;
    const int wid  = tid >> 6;
    const int wr = wid >> 1, wc = wid & 1;
    const int row0 = blockIdx.y * 128, col0 = blockIdx.x * 128;

    f32x4 acc[4][4];
#pragma unroll
    for (int m = 0; m < 4; ++m)
#pragma unroll
        for (int n = 0; n < 4; ++n) acc[m][n] = (f32x4)(0.f);

    const char* Abase = (const char*)(A + (size_t)row0 * K);
    const char* Bbase = (const char*)(Bt + (size_t)col0 * K);

    int srow[4], skb[4];
#pragma unroll
    for (int i = 0; i < 4; ++i) {
        unsigned o = (unsigned)(i * 256 + tid) * 16u;
        unsigned l = o ^ (((o >> 7) & 7u) << 4);
        srow[i] = (int)(l >> 7);
        skb[i]  = (int)(l & 127u);
    }

    for (int kt = 0; kt < K; kt += 64) {
#pragma unroll
        for (int i = 0; i < 4; ++i) {
            unsigned o = (unsigned)(i * 256 + tid) * 16u;
            gload_lds16(Abase + (size_t)srow[i] * (K * 2) + (size_t)kt * 2 + skb[i],
                        (char*)As + o);
            gload_lds16(Bbase + (size_t)srow[i] * (K * 2) + (size_t)kt * 2 + skb[i],
                        (char*)Bs + o);
        }
        asm volatile("s_waitcnt vmcnt(0)" ::: "memory");
        __syncthreads();
#pragma unroll
        for (int ks = 0; ks < 2; ++ks) {
            bf16x8 af[4], bfr[4];
#pragma unroll
            for (int m = 0; m < 4; ++m) {
                int row = wr * 64 + m * 16 + (lane & 15);
                unsigned o = (unsigned)(row * 128 + ks * 64 + ((lane >> 4) * 16));
                o ^= ((unsigned)(row & 7) << 4);
                af[m] = *(const bf16x8*)((const char*)As + o);
            }
#pragma unroll
            for (int n = 0; n < 4; ++n) {
                int col = wc * 64 + n * 16 + (lane & 15);
                unsigned o = (unsigned)(col * 128 + ks * 64 + ((lane >> 4) * 16));
                o ^= ((unsigned)(col & 7) << 4);
                bfr[n] = *(const bf16x8*)((const char*)Bs + o);
            }
#pragma unroll
            for (int m = 0; m < 4; ++m)
#pragma unroll
                for (int n = 0; n < 4; ++n)
                    acc[m][n] = __builtin_amdgcn_mfma_f32_16x16x32_bf16(
                        af[m], bfr[n], acc[m][n], 0, 0, 0);
        }
        __syncthreads();
    }

#pragma unroll
    for (int n = 0; n < 4; ++n) {
        int gcol = col0 + wc * 64 + n * 16 + (lane & 15);
        float bv = outF16 ? bias[gcol] : 0.f;
#pragma unroll
        for (int m = 0; m < 4; ++m) {
            int growb = row0 + wr * 64 + m * 16 + ((lane >> 4) * 4);
#pragma unroll
            for (int r = 0; r < 4; ++r) {
                float v = acc[m][n][r] + bv;
                size_t off = (size_t)(growb + r) * N + gcol;
                if (outF16)
                    ((unsigned short*)C)[off] =
                        __builtin_bit_cast(unsigned short, (_Float16)v);
                else
                    ((float*)C)[off] = v;
            }
        }
    }
}

// ---------------- RNN scan v10: SINGLE WAVE per chain, hybrid W store ----------------
// 64 blocks x 64 threads (1 wave). Lane owns cols 2l, 2l+1 over ALL 128 rows:
//   rows 0..63   : 64 f16x2 in VGPRs (r7-proven allocatable)
//   rows 64..127 : 16KB LDS, XOR-swizzled -> conflict-free ds_read_b128
// h: 64-dword LDS buffer; same-wave DS pipe ordering => NO barrier, NO DPP,
// full dot reduced in-lane. One ds_write + 16 broadcast h-reads + 16 W-reads
// + 128 fdot2 per step.
__global__ __attribute__((amdgpu_flat_work_group_size(64, 64),
                          amdgpu_waves_per_eu(1, 1))) void k_scan(
    const unsigned short* __restrict__ xpf,  // f16 [M_][DST]
    const float* __restrict__ h0,            // [B_][DST]
    const float* __restrict__ sw,            // [NH][HH][HH]
    unsigned short* __restrict__ hsb,        // bf16 [M_][DST]
    float* __restrict__ out_state) {         // [B_][DST]
    __shared__ __align__(16) unsigned hb[64];
    __shared__ __align__(16) unsigned wlA[2048];   // 8KB: rows 64..127, col c0
    __shared__ __align__(16) unsigned wlB[2048];   // 8KB: rows 64..127, col c0+1
    const int l = threadIdx.x;                // 0..63
    const int bb = blockIdx.x >> 4;
    const int nn = blockIdx.x & 15;
    const int c0 = l * 2;

    const float* wb = sw + (size_t)nn * HH * HH;

    // in-reg weights: rows 0..63 (row-pair j), both cols
    f16x2 wA[32], wB[32];
#pragma unroll
    for (int j = 0; j < 32; ++j) {
        float2 rA = *(const float2*)&wb[(size_t)(2 * j) * HH + c0];
        float2 rB = *(const float2*)&wb[(size_t)(2 * j + 1) * HH + c0];
        wA[j] = f16x2{(_Float16)rA.x, (_Float16)rB.x};
        wB[j] = f16x2{(_Float16)rA.y, (_Float16)rB.y};
    }
    // LDS weights: rows 64..127, swizzled (write matches b128 read pattern)
#pragma unroll
    for (int j = 0; j < 32; ++j) {
        float2 rA = *(const float2*)&wb[(size_t)(64 + 2 * j) * HH + c0];
        float2 rB = *(const float2*)&wb[(size_t)(64 + 2 * j + 1) * HH + c0];
        unsigned off = (unsigned)(l * 128) +
                       (((unsigned)(j >> 2) * 16u) ^ ((unsigned)(l & 7) << 4)) +
                       (unsigned)(j & 3) * 4u;
        *(unsigned*)((char*)wlA + off) = pk16((_Float16)rA.x, (_Float16)rB.x);
        *(unsigned*)((char*)wlB + off) = pk16((_Float16)rA.y, (_Float16)rB.y);
    }

    {   // h init: dword l = (h[2l], h[2l+1]) f16
        float2 h2 = *(const float2*)&h0[bb * DST + nn * HH + c0];
        hb[l] = pk16((_Float16)h2.x, (_Float16)h2.y);
    }

    const unsigned* xrow = (const unsigned*)(xpf + (size_t)bb * S_ * DST + nn * HH) + l;
    unsigned* hrow = (unsigned*)(hsb + (size_t)bb * S_ * DST + nn * HH) + l;
    float* osp = out_state + bb * DST + nn * HH + c0;

    unsigned x0 = xrow[0], x1 = xrow[1024], x2 = xrow[2048], x3 = xrow[3072];

    const uint4* hp = (const uint4*)hb;

    for (int t = 0; t < S_; ++t) {
        int tpf = (t + 4 < S_) ? t + 4 : S_ - 1;
        unsigned x4 = xrow[(size_t)tpf * 1024];

        float a0 = 0.f, a1 = 0.f, a2 = 0.f, a3 = 0.f;
        float b0 = 0.f, b1 = 0.f, b2 = 0.f, b3 = 0.f;

        // rows 0..63 (in-reg W): h dwords 0..31, broadcast reads
#pragma unroll
        for (int k = 0; k < 8; ++k) {
            uint4 H = hp[k];
            a0 = fdu(H.x, __builtin_bit_cast(unsigned, wA[4 * k + 0]), a0);
            b0 = fdu(H.x, __builtin_bit_cast(unsigned, wB[4 * k + 0]), b0);
            a1 = fdu(H.y, __builtin_bit_cast(unsigned, wA[4 * k + 1]), a1);
            b1 = fdu(H.y, __builtin_bit_cast(unsigned, wB[4 * k + 1]), b1);
            a2 = fdu(H.z, __builtin_bit_cast(unsigned, wA[4 * k + 2]), a2);
            b2 = fdu(H.z, __builtin_bit_cast(unsigned, wB[4 * k + 2]), b2);
            a3 = fdu(H.w, __builtin_bit_cast(unsigned, wA[4 * k + 3]), a3);
            b3 = fdu(H.w, __builtin_bit_cast(unsigned, wB[4 * k + 3]), b3);
        }
        // rows 64..127 (LDS W, swizzled): h dwords 32..63
#pragma unroll
        for (int k = 0; k < 8; ++k) {
            uint4 H = hp[8 + k];
            unsigned off = (unsigned)(l * 128) +
                           (((unsigned)k * 16u) ^ ((unsigned)(l & 7) << 4));
            uint4 WAc = *(const uint4*)((const char*)wlA + off);
            uint4 WBc = *(const uint4*)((const char*)wlB + off);
            a0 = fdu(H.x, WAc.x, a0); b0 = fdu(H.x, WBc.x, b0);
            a1 = fdu(H.y, WAc.y, a1); b1 = fdu(H.y, WBc.y, b1);
            a2 = fdu(H.z, WAc.z, a2); b2 = fdu(H.z, WBc.z, b2);
            a3 = fdu(H.w, WAc.w, a3); b3 = fdu(H.w, WBc.w, b3);
        }

        f16x2 xv = __builtin_bit_cast(f16x2, x0);
        float s0 = ((a0 + a1) + (a2 + a3)) + (float)xv.x;
        float s1 = ((b0 + b1) + (b2 + b3)) + (float)xv.y;
        // tanh(s) = 1 - 2/(exp(2s)+1), exact at +-inf
        float e0 = __builtin_amdgcn_exp2f(s0 * 2.885390081777927f);
        float e1 = __builtin_amdgcn_exp2f(s1 * 2.885390081777927f);
        float th0 = fmaf(-2.f, __builtin_amdgcn_rcpf(e0 + 1.f), 1.f);
        float th1 = fmaf(-2.f, __builtin_amdgcn_rcpf(e1 + 1.f), 1.f);

        // single wave: all reads above already issued -> in-order DS pipe
        // makes this write safe without any barrier.
        hb[l] = pk16((_Float16)th0, (_Float16)th1);
        hrow[(size_t)t * (DST / 2)] = (unsigned)f2bf(th0) | ((unsigned)f2bf(th1) << 16);
        if (t == S_ - 1) { osp[0] = th0; osp[1] = th1; }

        x0 = x1; x1 = x2; x2 = x3; x3 = x4;
    }
}

extern "C" void kernel_launch(void* const* d_in, const int* in_sizes, int n_in,
                              void* d_out, int out_size, void* d_ws, size_t ws_size,
                              hipStream_t stream) {
    const float* x    = (const float*)d_in[0];
    const float* h0   = (const float*)d_in[1];
    const float* Wi   = (const float*)d_in[2];
    const float* bias = (const float*)d_in[3];
    const float* sw   = (const float*)d_in[4];
    const float* Wo   = (const float*)d_in[5];
    float* out = (float*)d_out;

    char* ws = (char*)d_ws;
    unsigned short* xb  = (unsigned short*)ws;                 // 32MB (reused as hs)
    unsigned short* wit = (unsigned short*)(ws + 33554432);    // 8MB
    unsigned short* wot = (unsigned short*)(ws + 41943040);    // 8MB
    unsigned short* xpf = (unsigned short*)(ws + 50331648);    // 32MB f16 xp

    // 1. cast x -> bf16
    k_cast_bf16<<<8192, 256, 0, stream>>>(x, xb, (M_ * DIN) / 8);
    // 2. transpose+cast weights
    dim3 tg(32, 32);
    k_transpose_bf16<<<tg, 256, 0, stream>>>(Wi, wit, DIN, DST);
    k_transpose_bf16<<<tg, 256, 0, stream>>>(Wo, wot, DST, DOUT);
    // 3. xp(f16) = x @ Wi + b
    dim3 g1(DST / 128, M_ / 128);
    k_gemm_bt<<<g1, 256, 0, stream>>>(xb, wit, xpf, bias, M_, DST, DIN, 1);
    // 4. sequential scan (1 wave per chain, 64 blocks x 64 threads)
    k_scan<<<64, 64, 0, stream>>>(xpf, h0, sw, xb, out + OUT_OFF);
    // 5. out = hs @ Wo
    dim3 g2(DOUT / 128, M_ / 128);
    k_gemm_bt<<<g2, 256, 0, stream>>>(xb, wot, out, nullptr, M_, DOUT, DST, 0);
}